// Round 13
// baseline (193.279 us; speedup 1.0000x reference)
//
#include <hip/hip_runtime.h>
#include <math.h>

#define Bz 2
#define Tz 2048
#define Cz 1024
#define Hz 16
#define Dz 64

typedef unsigned short us;
typedef short bf16x8 __attribute__((ext_vector_type(8)));
typedef float f32x4  __attribute__((ext_vector_type(4)));
typedef float f32x16 __attribute__((ext_vector_type(16)));

__device__ __forceinline__ us f2bf(float f) {
    union { float f; unsigned u; } v; v.f = f;
    unsigned r = v.u + 0x7fffu + ((v.u >> 16) & 1u);   // RNE
    return (us)(r >> 16);
}

__device__ __forceinline__ float fexp2(float x) {
#if __has_builtin(__builtin_amdgcn_exp2f)
    return __builtin_amdgcn_exp2f(x);   // raw v_exp_f32 (2^x)
#else
    return exp2f(x);
#endif
}

// v_permlane32_swap_b32 a, b: exchanges a[32:63] <-> b[0:31]
// lo lane: a'=own a, b'=hi-partner's a.  hi lane: a'=lo-partner's b, b'=own b.
__device__ __forceinline__ void pl32swap(unsigned &a, unsigned &b) {
    asm("v_permlane32_swap_b32 %0, %1" : "+v"(a), "+v"(b));
}

// async global->LDS, 16B per lane; LDS dest = wave-uniform base + lane*16
#define GLD16(gp, lp) __builtin_amdgcn_global_load_lds( \
    (const __attribute__((address_space(1))) unsigned int*)(gp), \
    (__attribute__((address_space(3))) unsigned int*)(lp), 16, 0, 0)

// ---------------------------------------------------------------------------
// FRAGMENT-LINEAR K/V TILE LAYOUT (r6): per head, per 64-key tile (8KB),
// 16B chunks stored in exactly the order attn's wave reads them ->
// every kf/vf fragment load is base + lane*16B = contiguous 1KB/instr.
// Session lessons: r9 fusion forces min-occupancy (no); r10 XCD swizzle on
// L3-resident GEMMs adds fetch (no); r11 1 wave/SIMD TLP collapse (no);
// r12 QKV 8-wave: −6us by graph-truth (rocprof dispatch times inflated —
// trust dur_us A/B only). r13: one-pass grid (tail elimination).
// ---------------------------------------------------------------------------

// ---------------------------------------------------------------------------
// cast fp32 -> bf16: x (4M elems), wq,wk,wv (into wqkvb), wp (into wpb)
// ---------------------------------------------------------------------------
__global__ __launch_bounds__(256)
void cast_all(const float* __restrict__ x,  const float* __restrict__ wq,
              const float* __restrict__ wk, const float* __restrict__ wv,
              const float* __restrict__ wp,
              us* __restrict__ xb, us* __restrict__ wqkvb, us* __restrict__ wpb)
{
    const size_t M1 = 1u << 20;
    size_t i = ((size_t)blockIdx.x * 256 + threadIdx.x) * 4;
    const float* s; us* d; size_t o;
    int reg = (int)(i >> 20);
    if      (reg < 4)  { s = x;  d = xb;           o = i;          }
    else if (reg == 4) { s = wq; d = wqkvb;        o = i - 4 * M1; }
    else if (reg == 5) { s = wk; d = wqkvb + M1;   o = i - 5 * M1; }
    else if (reg == 6) { s = wv; d = wqkvb + 2*M1; o = i - 6 * M1; }
    else               { s = wp; d = wpb;          o = i - 7 * M1; }
    float4 v = *(const float4*)&s[o];
    ushort4 u;
    u.x = f2bf(v.x); u.y = f2bf(v.y); u.z = f2bf(v.z); u.w = f2bf(v.w);
    *(ushort4*)&d[o] = u;
}

// ---------------------------------------------------------------------------
// QKV GEMM (r13): 128x192 tile, 6 waves (384 thr, wr{0,1} x wc{0,1,2}),
// BK=64, XOR-swizzled LDS, dbuf counted-vmcnt pipeline (r7 schedule).
// Grid 16x32 = 512 blocks at 80KB LDS = EXACTLY 2 blocks/CU -> one uniform
// occupancy pass (r12's 768-block grid ran a 256-block tail at 1 block/CU).
// Staging: 40 GLD16/step (A 16 + B 24) distributed 7/7/7/7/6/6 by wave;
// per-wave counted vmcnt(7)/vmcnt(6).
// out[m,n] = sum_k A[m,k]*W[n,k] + bias[n]
// Epilogue: Q -> [B,H,T,D] * 0.125*log2e ; K,V -> fragment-linear
// ---------------------------------------------------------------------------
__global__ __launch_bounds__(384)
void qkv_gemm(const us* __restrict__ A, const us* __restrict__ W,
              const float* __restrict__ b0, const float* __restrict__ b1,
              const float* __restrict__ b2,
              us* __restrict__ outQ, us* __restrict__ outK, us* __restrict__ outV)
{
    __shared__ us As[2][128][64];
    __shared__ us Bs[2][192][64];
    const int t = threadIdx.x, w = t >> 6, l = t & 63;
    const int m0 = blockIdx.y * 128;
    const int n0 = blockIdx.x * 192;
    const int wr = w / 3, wc = w % 3;         // wave -> 64x64 out sub-tile
    const int g = l >> 4, ln = l & 15;
    const int lrow  = l >> 3;                 // 0..7 within one GLD16
    const int lcolb = (l & 7) ^ lrow;         // swizzled source col-block
    const int xm = ln & 7;                    // reader xor mask (row&7 == ln&7)

    f32x4 acc[4][4];
#pragma unroll
    for (int i = 0; i < 4; ++i)
#pragma unroll
        for (int j = 0; j < 4; ++j) acc[i][j] = (f32x4){0.f, 0.f, 0.f, 0.f};

    // 40 staging instrs: q<16 -> A rows q*8; else B rows (q-16)*8.
    auto stage = [&](int bsel, int k0) {
#pragma unroll
        for (int p = 0; p < 7; ++p) {
            const int q = w + 6 * p;
            if (q < 40) {
                if (q < 16)
                    GLD16(A + (size_t)(m0 + q * 8 + lrow) * 1024 + k0 + lcolb * 8,
                          (us*)As[bsel] + q * 8 * 64);
                else {
                    const int rb = (q - 16) * 8;
                    GLD16(W + (size_t)(n0 + rb + lrow) * 1024 + k0 + lcolb * 8,
                          (us*)Bs[bsel] + rb * 64);
                }
            }
        }
    };

    stage(0, 0);                              // prologue
    for (int it = 0; it < 16; ++it) {
        stage((it + 1) & 1, (it < 15 ? it + 1 : 15) * 64);   // prefetch next
        if (w < 4) asm volatile("s_waitcnt vmcnt(7)" ::: "memory");
        else       asm volatile("s_waitcnt vmcnt(6)" ::: "memory");
        __builtin_amdgcn_s_barrier();         // buf[it&1] ready (all waves)
        __builtin_amdgcn_sched_barrier(0);    // no ds_read hoisting above
        const int cb = it & 1;
#pragma unroll
        for (int kk = 0; kk < 2; ++kk) {
            bf16x8 af[4], bf[4];
#pragma unroll
            for (int i = 0; i < 4; ++i)
                af[i] = *(const bf16x8*)&As[cb][wr * 64 + i * 16 + ln][((kk * 4 + g) ^ xm) * 8];
#pragma unroll
            for (int j = 0; j < 4; ++j)
                bf[j] = *(const bf16x8*)&Bs[cb][wc * 64 + j * 16 + ln][((kk * 4 + g) ^ xm) * 8];
#pragma unroll
            for (int i = 0; i < 4; ++i)
#pragma unroll
                for (int j = 0; j < 4; ++j)
                    acc[i][j] = __builtin_amdgcn_mfma_f32_16x16x32_bf16(af[i], bf[j], acc[i][j], 0, 0, 0);
        }
        asm volatile("s_waitcnt lgkmcnt(0)" ::: "memory");   // reads done
        __builtin_amdgcn_s_barrier();         // before next stage overwrites
    }
    asm volatile("s_waitcnt vmcnt(0)" ::: "memory");  // drain last (dummy) stage
    __syncthreads();

    // ---- epilogue: per-wave 64-col slab (aligned to Q/K/V boundaries) ----
    const float QSC = 0.125f * 1.44269504088896f;   // fold log2e: 2^ domain softmax
    const int gn0  = n0 + wc * 64;
    const int sel  = gn0 >> 10;          // 0=Q 1=K 2=V (wave uniform)
    const int rem0 = gn0 & 1023;
    const int h    = rem0 >> 6;
    const float* bsrc = (sel == 0) ? b0 : ((sel == 1) ? b1 : b2);
    float bj[4];
#pragma unroll
    for (int j = 0; j < 4; ++j) bj[j] = bsrc[rem0 + j * 16 + ln];

    if (sel == 2) {
        // V -> fragment-linear Vf (8B stores, 16B-stride runs)
#pragma unroll
        for (int i = 0; i < 4; ++i)
#pragma unroll
            for (int j = 0; j < 4; ++j) {
                const int dd  = j * 16 + ln;        // d within head
                const int gm0 = m0 + wr * 64 + i * 16 + g * 4;
                const int b = gm0 >> 11, t0 = gm0 & 2047;
                const int tile = t0 >> 6, tt = t0 & 63;
                const int ks = tt >> 4, hi2 = (tt >> 3) & 1, e = tt & 7;
                const int j32 = dd >> 5, qc = dd & 31;
                ushort4 pk;
                pk.x = f2bf(acc[i][j][0] + bj[j]); pk.y = f2bf(acc[i][j][1] + bj[j]);
                pk.z = f2bf(acc[i][j][2] + bj[j]); pk.w = f2bf(acc[i][j][3] + bj[j]);
                const size_t off = (size_t)(b * Hz + h) * (Tz * Dz)
                                 + tile * 4096 + ((j32 * 4 + ks) * 2 + hi2) * 256 + qc * 8 + e;
                *(ushort4*)&outV[off] = pk;   // e in {0,4}: 8B-aligned, in-chunk
            }
    } else {
        // Q -> [B,H,T,D] rows; K -> fragment-linear Kf (LDS transpose)
        us* dst = (sel == 0) ? outQ : outK;
        us* scrw = ((us*)As) + w * (16 * 72);  // 2.25KB/wave scratch (6x = 13.5KB)
        const int row16 = l & 15, ch = l >> 4;
#pragma unroll
        for (int i = 0; i < 4; ++i) {
#pragma unroll
            for (int j = 0; j < 4; ++j)
#pragma unroll
                for (int r = 0; r < 4; ++r) {
                    float v = acc[i][j][r] + bj[j];
                    if (sel == 0) v *= QSC;
                    scrw[(g * 4 + r) * 72 + j * 16 + ln] = f2bf(v);
                }
            // same-wave LDS ordering: reads below see this wave's writes
            const int gm = m0 + wr * 64 + i * 16 + row16;
            const int b = gm >> 11, tt = gm & 2047;
            bf16x8 v0 = *(const bf16x8*)&scrw[row16 * 72 + ch * 8];
            bf16x8 v1 = *(const bf16x8*)&scrw[row16 * 72 + (ch + 4) * 8];
            if (sel == 0) {
                const size_t base = (size_t)((b * Hz + h) * Tz + tt) * Dz;
                *(bf16x8*)&dst[base + ch * 8] = v0;
                *(bf16x8*)&dst[base + (ch + 4) * 8] = v1;
            } else {
                const int tile = tt >> 6, rr = tt & 63;
                const int kb32 = rr >> 5, qc = rr & 31;
                const size_t tb = (size_t)(b * Hz + h) * (Tz * Dz) + tile * 4096;
                *(bf16x8*)&dst[tb + (kb32 * 8 + ch) * 256 + qc * 8]       = v0;
                *(bf16x8*)&dst[tb + (kb32 * 8 + ch + 4) * 256 + qc * 8]   = v1;
            }
        }
    }
}

// ---------------------------------------------------------------------------
// Output-projection GEMM (r7 best config): tile (WR*AI*16) x 128, dbuf
// counted-vmcnt. AI=2, WR=2 -> 64x128, 4 waves, 48KB, 3 blocks/CU.
// ---------------------------------------------------------------------------
template<int AI, int WR>
__global__ __launch_bounds__(WR * 128)
void proj_gemm(const us* __restrict__ A, const us* __restrict__ W,
               const float* __restrict__ b0, float* __restrict__ od)
{
    constexpr int TR = WR * AI * 16;      // tile rows
    constexpr int PB = 8 / WR;            // B-stage GLD16 per wave
    constexpr int VC = AI + PB;           // in-flight loads per stage per wave
    __shared__ us As[2][TR][64];
    __shared__ us Bs[2][128][64];
    const int t = threadIdx.x, w = t >> 6, l = t & 63;
    const int m0 = blockIdx.y * TR;
    const int n0 = blockIdx.x * 128;
    const int wr = w >> 1, wc = w & 1;
    const int g = l >> 4, ln = l & 15;
    const int lrow  = l >> 3;
    const int lcolb = (l & 7) ^ lrow;
    const int xm = ln & 7;

    f32x4 acc[AI][4];
#pragma unroll
    for (int i = 0; i < AI; ++i)
#pragma unroll
        for (int j = 0; j < 4; ++j) acc[i][j] = (f32x4){0.f, 0.f, 0.f, 0.f};

    auto stage = [&](int bsel, int k0) {
#pragma unroll
        for (int p = 0; p < AI; ++p) {
            const int rb = (w * AI + p) * 8;
            GLD16(A + (size_t)(m0 + rb + lrow) * 1024 + k0 + lcolb * 8,
                  (us*)As[bsel] + rb * 64);
        }
#pragma unroll
        for (int p = 0; p < PB; ++p) {
            const int rb = (w * PB + p) * 8;
            GLD16(W + (size_t)(n0 + rb + lrow) * 1024 + k0 + lcolb * 8,
                  (us*)Bs[bsel] + rb * 64);
        }
    };

    stage(0, 0);
    for (int it = 0; it < 16; ++it) {
        stage((it + 1) & 1, (it < 15 ? it + 1 : 15) * 64);
        if constexpr (VC == 4)      asm volatile("s_waitcnt vmcnt(4)" ::: "memory");
        else if constexpr (VC == 6) asm volatile("s_waitcnt vmcnt(6)" ::: "memory");
        else                        asm volatile("s_waitcnt vmcnt(8)" ::: "memory");
        __builtin_amdgcn_s_barrier();
        __builtin_amdgcn_sched_barrier(0);
        const int cb = it & 1;
#pragma unroll
        for (int kk = 0; kk < 2; ++kk) {
            bf16x8 af[AI], bf[4];
#pragma unroll
            for (int i = 0; i < AI; ++i)
                af[i] = *(const bf16x8*)&As[cb][wr * (AI * 16) + i * 16 + ln][((kk * 4 + g) ^ xm) * 8];
#pragma unroll
            for (int j = 0; j < 4; ++j)
                bf[j] = *(const bf16x8*)&Bs[cb][wc * 64 + j * 16 + ln][((kk * 4 + g) ^ xm) * 8];
#pragma unroll
            for (int i = 0; i < AI; ++i)
#pragma unroll
                for (int j = 0; j < 4; ++j)
                    acc[i][j] = __builtin_amdgcn_mfma_f32_16x16x32_bf16(af[i], bf[j], acc[i][j], 0, 0, 0);
        }
        asm volatile("s_waitcnt lgkmcnt(0)" ::: "memory");
        __builtin_amdgcn_s_barrier();
    }
    asm volatile("s_waitcnt vmcnt(0)" ::: "memory");
    __syncthreads();

#pragma unroll
    for (int i = 0; i < AI; ++i)
#pragma unroll
        for (int j = 0; j < 4; ++j) {
            const int gn = n0 + wc * 64 + j * 16 + ln;
            const float bjv = b0[gn];
#pragma unroll
            for (int r = 0; r < 4; ++r) {
                const int gm = m0 + wr * (AI * 16) + i * 16 + g * 4 + r;
                od[(size_t)gm * 1024 + gn] = acc[i][j][r] + bjv;
            }
        }
}

// ---------------------------------------------------------------------------
// Wave-flash attention (r6, passing): 32x32 swapped QK^T, in-register
// softmax (T12), fragment-linear K/V, 4-way K-split + LDS merge tree.
// __launch_bounds__(256,3): do not raise (r1: ~85-reg budget => 673MB spill).
// ---------------------------------------------------------------------------
__global__ __launch_bounds__(256, 3)
void attn_wave(const us* __restrict__ Q, const us* __restrict__ K,
               const us* __restrict__ Vt, us* __restrict__ AO)
{
    __shared__ float Om[2][32][65];   // merge: 16.6 KB
    __shared__ float Lw[2][32];       // merge row-sums

    const int t = threadIdx.x, w = t >> 6, l = t & 63;
    const int qc = l & 31;            // q-col (QK) / d-col (PV)
    const int hi = l >> 5;
    const int hi8 = hi << 3, hi4 = hi << 2;
    const int bh = blockIdx.x;                       // head pinned to XCD bh%8
    const int chunk = 63 - (int)blockIdx.y;          // heavy first
    const int q0 = chunk * 32;
    const size_t hb = (size_t)bh * Tz * Dz;

    const int ntiles = (q0 >> 6) + 1;
    const int it0 = (w * ntiles) >> 2;               // wave w: [it0, it1)
    const int it1 = ((w + 1) * ntiles) >> 2;

    // Q B-frags: n = q0+qc, k-pos (hi,j) -> d = kb*16 + 8hi + j  (rows: [T,D])
    bf16x8 qf[4];
#pragma unroll
    for (int kb = 0; kb < 4; ++kb)
        qf[kb] = *(const bf16x8*)&Q[hb + (size_t)(q0 + qc) * Dz + kb * 16 + hi8];

    f32x16 o0, o1;                    // O[q(reg,hi)][d = {0,1}*32 + qc]
    float lrs = 0.f;                  // own-half row-sum for q = q0+qc
#pragma unroll
    for (int r = 0; r < 16; ++r) { o0[r] = 0.f; o1[r] = 0.f; }

    const int ktLast = (q0 >> 6) << 6;
    const float SMAX = 20.f;          // static max (log2 domain)

    for (int it = it0; it < it1; ++it) {
        const int kt = it * 64;
        const size_t tb = hb + (size_t)it * 4096;    // fragment-linear tile base

        // K A-frags: contiguous, lane l at +l*8 elems
        bf16x8 kf[2][4];
#pragma unroll
        for (int kb32 = 0; kb32 < 2; ++kb32)
#pragma unroll
            for (int kb = 0; kb < 4; ++kb)
                kf[kb32][kb] = *(const bf16x8*)&K[tb + (size_t)((kb32 * 4 + kb) * 64 + l) * 8];

        // S^T = K Q^T : col = q, reg-rows = key
        f32x16 s2[2];
#pragma unroll
        for (int r = 0; r < 16; ++r) { s2[0][r] = 0.f; s2[1][r] = 0.f; }
        __builtin_amdgcn_s_setprio(1);
#pragma unroll
        for (int kb32 = 0; kb32 < 2; ++kb32)
#pragma unroll
            for (int kb = 0; kb < 4; ++kb)
                s2[kb32] = __builtin_amdgcn_mfma_f32_32x32x16_bf16(kf[kb32][kb], qf[kb], s2[kb32], 0, 0, 0);
        __builtin_amdgcn_s_setprio(0);

        // V B-frags: contiguous; issue now, land during softmax
        bf16x8 vf[2][4];
#pragma unroll
        for (int j32 = 0; j32 < 2; ++j32)
#pragma unroll
            for (int ks = 0; ks < 4; ++ks)
                vf[j32][ks] = *(const bf16x8*)&Vt[tb + (size_t)((j32 * 4 + ks) * 64 + l) * 8];

        if (kt == ktLast) {   // diagonal tile: causal mask (wave-uniform branch)
            const int qv = q0 + qc;
#pragma unroll
            for (int kb32 = 0; kb32 < 2; ++kb32)
#pragma unroll
                for (int r = 0; r < 16; ++r) {
                    const int key = kt + kb32 * 32 + (r & 3) + 8 * (r >> 2) + hi4;
                    if (key > qv) s2[kb32][r] = -__builtin_inff();
                }
        }

        // in-register softmax + P->A-frag transpose (no LDS)
        bf16x8 pf[4];
#pragma unroll
        for (int kb32 = 0; kb32 < 2; ++kb32) {
            unsigned pk[4][2];
#pragma unroll
            for (int sg = 0; sg < 4; ++sg)
#pragma unroll
                for (int u = 0; u < 2; ++u) {
                    const float e0 = fexp2(s2[kb32][sg * 4 + 2 * u]     - SMAX);  // -inf -> 0
                    const float e1 = fexp2(s2[kb32][sg * 4 + 2 * u + 1] - SMAX);
                    lrs += e0 + e1;
                    pk[sg][u] = __builtin_amdgcn_perm(__float_as_uint(e1), __float_as_uint(e0), 0x07060302u);
                }
            // swap(a=even_sg, b=odd_sg): a' = frag dwords j{2u,2u+1}, b' = j{4+2u,5+2u}
#pragma unroll
            for (int kb16 = 0; kb16 < 2; ++kb16) {
                unsigned a0 = pk[2 * kb16][0], b0 = pk[2 * kb16 + 1][0];
                unsigned a1 = pk[2 * kb16][1], b1 = pk[2 * kb16 + 1][1];
                pl32swap(a0, b0);
                pl32swap(a1, b1);
                union { unsigned u[4]; bf16x8 v; } P;
                P.u[0] = a0; P.u[1] = a1; P.u[2] = b0; P.u[3] = b1;
                pf[kb32 * 2 + kb16] = P.v;
            }
        }

        // PV: O[q][d], A = pf (m=q), B = vf (n=d)
        __builtin_amdgcn_s_setprio(1);
#pragma unroll
        for (int ks = 0; ks < 4; ++ks) {
            o0 = __builtin_amdgcn_mfma_f32_32x32x16_bf16(pf[ks], vf[0][ks], o0, 0, 0, 0);
            o1 = __builtin_amdgcn_mfma_f32_32x32x16_bf16(pf[ks], vf[1][ks], o1, 0, 0, 0);
        }
        __builtin_amdgcn_s_setprio(0);
    }

    // combine half row-sums: partner's value arrives in b' on lo, a' on hi.
    {
        unsigned a = __float_as_uint(lrs), b = a;
        pl32swap(a, b);
        lrs += hi ? __uint_as_float(a) : __uint_as_float(b);
    }

    // ---- merge the 4 K-split partials (same static max -> plain sums) ----
    if (w & 1) {       // waves 1,3 park into buf w>>1
        const int buf = w >> 1;
#pragma unroll
        for (int r = 0; r < 16; ++r) {
            const int row = (r & 3) + 8 * (r >> 2) + hi4;
            Om[buf][row][qc]      = o0[r];
            Om[buf][row][32 + qc] = o1[r];
        }
        if (hi == 0) Lw[buf][qc] = lrs;
    }
    __syncthreads();
    if (!(w & 1)) {    // waves 0,2 absorb their odd buddy
        const int buf = w >> 1;
#pragma unroll
        for (int r = 0; r < 16; ++r) {
            const int row = (r & 3) + 8 * (r >> 2) + hi4;
            o0[r] += Om[buf][row][qc];
            o1[r] += Om[buf][row][32 + qc];
        }
        lrs += Lw[buf][qc];
    }
    __syncthreads();
    if (w == 2) {      // park the (2+3) partial for wave 0
#pragma unroll
        for (int r = 0; r < 16; ++r) {
            const int row = (r & 3) + 8 * (r >> 2) + hi4;
            Om[0][row][qc]      = o0[r];
            Om[0][row][32 + qc] = o1[r];
        }
        if (hi == 0) Lw[0][qc] = lrs;
    }
    __syncthreads();
    if (w == 0) {      // final sum, normalize (bpermute broadcast), write
        const int b = bh >> 4, h = bh & 15;
        const float lsum = lrs + Lw[0][qc];   // full row-sum for q = q0+qc
#pragma unroll
        for (int r = 0; r < 16; ++r) {
            const int row = (r & 3) + 8 * (r >> 2) + hi4;
            const float ov0 = o0[r] + Om[0][row][qc];
            const float ov1 = o1[r] + Om[0][row][32 + qc];
            const unsigned lq = __builtin_amdgcn_ds_bpermute(row << 2, __float_as_uint(lsum));
            const float linv = 1.f / __uint_as_float(lq);
            const size_t ob = (size_t)(b * Tz + q0 + row) * Cz + h * Dz + qc;
            AO[ob]      = f2bf(ov0 * linv);
            AO[ob + 32] = f2bf(ov1 * linv);
        }
    }
}

// ---------------------------------------------------------------------------
extern "C" void kernel_launch(void* const* d_in, const int* in_sizes, int n_in,
                              void* d_out, int out_size, void* d_ws, size_t ws_size,
                              hipStream_t stream) {
    const float* x  = (const float*)d_in[0];
    // d_in[1] = att_mask (causal tril) — implied by kernel structure, unused
    const float* wq = (const float*)d_in[2];
    const float* bq = (const float*)d_in[3];
    const float* wk = (const float*)d_in[4];
    const float* bk = (const float*)d_in[5];
    const float* wv = (const float*)d_in[6];
    const float* bv = (const float*)d_in[7];
    const float* wp = (const float*)d_in[8];
    const float* bp = (const float*)d_in[9];
    float* out = (float*)d_out;

    char* wsb = (char*)d_ws;
    us* xb    = (us*)(wsb);                       // 8 MB
    us* wqkvb = (us*)(wsb + (8u  << 20));         // 6 MB
    us* wpb   = (us*)(wsb + (14u << 20));         // 2 MB
    us* Qb    = (us*)(wsb + (17u << 20));         // 8 MB
    us* Kb    = (us*)(wsb + (25u << 20));         // 8 MB (fragment-linear)
    us* Vtb   = (us*)(wsb + (33u << 20));         // 8 MB (fragment-linear)
    us* AOb   = (us*)(wsb + (41u << 20));         // 8 MB

    hipLaunchKernelGGL(cast_all, dim3(8192), dim3(256), 0, stream,
                       x, wq, wk, wv, wp, xb, wqkvb, wpb);

    // fused QKV: [4096 x 3072 x 1024], 128x192 tile, 6 waves, 80KB LDS:
    // 512 blocks = exactly 2 blocks/CU, one uniform occupancy pass
    hipLaunchKernelGGL(qkv_gemm, dim3(16, 32), dim3(384), 0, stream,
                       xb, wqkvb, bq, bk, bv, Qb, Kb, Vtb);

    // attention: 32x32 swapped-QK^T, in-register softmax, contiguous frag loads
    hipLaunchKernelGGL(attn_wave, dim3(32, 64), dim3(256), 0, stream,
                       Qb, Kb, Vtb, AOb);

    // output projection: r7 best config (64x128, 4 waves, 3 blocks/CU)
    hipLaunchKernelGGL((proj_gemm<2, 2>), dim3(8, 64), dim3(256), 0, stream,
                       AOb, wpb, bp, out);
}

// Round 14
// 179.521 us; speedup vs baseline: 1.0766x; 1.0766x over previous
//
#include <hip/hip_runtime.h>
#include <math.h>

#define Bz 2
#define Tz 2048
#define Cz 1024
#define Hz 16
#define Dz 64

typedef unsigned short us;
typedef short bf16x8 __attribute__((ext_vector_type(8)));
typedef float f32x4  __attribute__((ext_vector_type(4)));
typedef float f32x16 __attribute__((ext_vector_type(16)));

__device__ __forceinline__ us f2bf(float f) {
    union { float f; unsigned u; } v; v.f = f;
    unsigned r = v.u + 0x7fffu + ((v.u >> 16) & 1u);   // RNE
    return (us)(r >> 16);
}

__device__ __forceinline__ float fexp2(float x) {
#if __has_builtin(__builtin_amdgcn_exp2f)
    return __builtin_amdgcn_exp2f(x);   // raw v_exp_f32 (2^x)
#else
    return exp2f(x);
#endif
}

// v_permlane32_swap_b32 a, b: exchanges a[32:63] <-> b[0:31]
// lo lane: a'=own a, b'=hi-partner's a.  hi lane: a'=lo-partner's b, b'=own b.
__device__ __forceinline__ void pl32swap(unsigned &a, unsigned &b) {
    asm("v_permlane32_swap_b32 %0, %1" : "+v"(a), "+v"(b));
}

// async global->LDS, 16B per lane; LDS dest = wave-uniform base + lane*16
#define GLD16(gp, lp) __builtin_amdgcn_global_load_lds( \
    (const __attribute__((address_space(1))) unsigned int*)(gp), \
    (__attribute__((address_space(3))) unsigned int*)(lp), 16, 0, 0)

// ---------------------------------------------------------------------------
// FRAGMENT-LINEAR K/V TILE LAYOUT (r6): per head, per 64-key tile (8KB),
// 16B chunks stored in exactly the order attn's wave reads them ->
// every kf/vf fragment load is base + lane*16B = contiguous 1KB/instr.
// Session lessons (all measured):
//  r9  single-kernel fusion forces min-occupancy across stages -> NO
//  r10 XCD swizzle on L3-resident GEMMs adds fetch (+13us)      -> NO
//  r11 1 wave/SIMD TLP collapse (proj AI=4, 256 blocks)         -> NO
//  r12 QKV 8 waves (4 waves/SIMD): -6us graph-truth             -> YES (this)
//  r13 128x192/6-wave: waves/SIMD 4->3 + heavier staging, +13us -> NO
// TLP (waves/SIMD) is the binding resource; trust dur_us A/B only
// (rocprof dispatch durations are inflated/inconsistent under replay).
// ---------------------------------------------------------------------------

// ---------------------------------------------------------------------------
// cast fp32 -> bf16: x (4M elems), wq,wk,wv (into wqkvb), wp (into wpb)
// ---------------------------------------------------------------------------
__global__ __launch_bounds__(256)
void cast_all(const float* __restrict__ x,  const float* __restrict__ wq,
              const float* __restrict__ wk, const float* __restrict__ wv,
              const float* __restrict__ wp,
              us* __restrict__ xb, us* __restrict__ wqkvb, us* __restrict__ wpb)
{
    const size_t M1 = 1u << 20;
    size_t i = ((size_t)blockIdx.x * 256 + threadIdx.x) * 4;
    const float* s; us* d; size_t o;
    int reg = (int)(i >> 20);
    if      (reg < 4)  { s = x;  d = xb;           o = i;          }
    else if (reg == 4) { s = wq; d = wqkvb;        o = i - 4 * M1; }
    else if (reg == 5) { s = wk; d = wqkvb + M1;   o = i - 5 * M1; }
    else if (reg == 6) { s = wv; d = wqkvb + 2*M1; o = i - 6 * M1; }
    else               { s = wp; d = wpb;          o = i - 7 * M1; }
    float4 v = *(const float4*)&s[o];
    ushort4 u;
    u.x = f2bf(v.x); u.y = f2bf(v.y); u.z = f2bf(v.z); u.w = f2bf(v.w);
    *(ushort4*)&d[o] = u;
}

// ---------------------------------------------------------------------------
// bf16 MFMA GEMM, tile (WR*AI*16) x 128, BK=64, XOR-swizzled LDS, dbuf with
// COUNTED vmcnt (r7 pipeline: stage next -> vmcnt(VC) -> raw s_barrier ->
// MFMA -> lgkmcnt(0) -> s_barrier; never drain vmcnt to 0 in the loop).
// WR = row-quadrants (waves = WR*2, block = WR*128 threads).
//   QKV (r12 best): AI=2, WR=4 -> 128x128 tile, 8 waves, 512 thr, 64KB LDS,
//     2 blocks/CU -> 16 waves/CU = 4 waves/SIMD.
//   proj (r7 best): AI=2, WR=2 -> 64x128, 4 waves, 48KB, 3 blocks/CU.
// out[m,n] = sum_k A[m,k]*W[n,k] + bias[n]
// EPI 0 (N=3072): Q -> [B,H,T,D] * 0.125*log2e ; K,V -> fragment-linear
// EPI 1 (N=1024): fp32 out [Mz,1024]
// ---------------------------------------------------------------------------
template<int AI, int WR, int EPI>
__global__ __launch_bounds__(WR * 128)
void mfma_gemm(const us* __restrict__ A, const us* __restrict__ W,
               const float* __restrict__ b0, const float* __restrict__ b1,
               const float* __restrict__ b2,
               void* out0, void* out1, void* out2)
{
    constexpr int TR = WR * AI * 16;      // tile rows
    constexpr int PB = 8 / WR;            // B-stage GLD16 per wave
    constexpr int VC = AI + PB;           // in-flight loads per stage per wave
    __shared__ us As[2][TR][64];
    __shared__ us Bs[2][128][64];
    const int t = threadIdx.x, w = t >> 6, l = t & 63;
    const int m0 = blockIdx.y * TR;
    const int n0 = blockIdx.x * 128;
    const int wr = w >> 1, wc = w & 1;    // wr in [0,WR), wc in {0,1}
    const int g = l >> 4, ln = l & 15;
    const int lrow  = l >> 3;                 // 0..7 within one GLD16
    const int lcolb = (l & 7) ^ lrow;         // swizzled source col-block
    const int xm = ln & 7;                    // reader xor mask (row&7 == ln&7)

    f32x4 acc[AI][4];
#pragma unroll
    for (int i = 0; i < AI; ++i)
#pragma unroll
        for (int j = 0; j < 4; ++j) acc[i][j] = (f32x4){0.f, 0.f, 0.f, 0.f};

    auto stage = [&](int bsel, int k0) {
#pragma unroll
        for (int p = 0; p < AI; ++p) {        // A: TR rows, 8 rows/instr
            const int rb = (w * AI + p) * 8;
            GLD16(A + (size_t)(m0 + rb + lrow) * 1024 + k0 + lcolb * 8,
                  (us*)As[bsel] + rb * 64);
        }
#pragma unroll
        for (int p = 0; p < PB; ++p) {        // B: 128 rows
            const int rb = (w * PB + p) * 8;
            GLD16(W + (size_t)(n0 + rb + lrow) * 1024 + k0 + lcolb * 8,
                  (us*)Bs[bsel] + rb * 64);
        }
    };

    stage(0, 0);                              // prologue
    for (int it = 0; it < 16; ++it) {
        stage((it + 1) & 1, (it < 15 ? it + 1 : 15) * 64);   // prefetch next
        if constexpr (VC == 4)      asm volatile("s_waitcnt vmcnt(4)" ::: "memory");
        else if constexpr (VC == 6) asm volatile("s_waitcnt vmcnt(6)" ::: "memory");
        else                        asm volatile("s_waitcnt vmcnt(8)" ::: "memory");
        __builtin_amdgcn_s_barrier();         // buf[it&1] ready (all waves)
        __builtin_amdgcn_sched_barrier(0);    // no ds_read hoisting above
        const int cb = it & 1;
#pragma unroll
        for (int kk = 0; kk < 2; ++kk) {
            bf16x8 af[AI], bf[4];
#pragma unroll
            for (int i = 0; i < AI; ++i)
                af[i] = *(const bf16x8*)&As[cb][wr * (AI * 16) + i * 16 + ln][((kk * 4 + g) ^ xm) * 8];
#pragma unroll
            for (int j = 0; j < 4; ++j)
                bf[j] = *(const bf16x8*)&Bs[cb][wc * 64 + j * 16 + ln][((kk * 4 + g) ^ xm) * 8];
#pragma unroll
            for (int i = 0; i < AI; ++i)
#pragma unroll
                for (int j = 0; j < 4; ++j)
                    acc[i][j] = __builtin_amdgcn_mfma_f32_16x16x32_bf16(af[i], bf[j], acc[i][j], 0, 0, 0);
        }
        asm volatile("s_waitcnt lgkmcnt(0)" ::: "memory");   // reads done
        __builtin_amdgcn_s_barrier();         // before next stage overwrites
    }
    asm volatile("s_waitcnt vmcnt(0)" ::: "memory");  // drain last (dummy) stage
    __syncthreads();

    if (EPI == 0) {
        const float QSC = 0.125f * 1.44269504088896f;   // fold log2e: 2^ domain softmax
        const int gn0  = n0 + wc * 64;       // wave's 64-col slab: one head, dd 0..63
        const int sel  = gn0 >> 10;          // 0=Q 1=K 2=V (block/wave uniform)
        const int rem0 = gn0 & 1023;
        const int h    = rem0 >> 6;
        const float* bsrc = (sel == 0) ? b0 : ((sel == 1) ? b1 : b2);
        float bj[4];
#pragma unroll
        for (int j = 0; j < 4; ++j) bj[j] = bsrc[rem0 + j * 16 + ln];

        if (sel == 2) {
            // V -> fragment-linear Vf (8B stores, 16B-stride runs)
            us* vd = (us*)out2;
#pragma unroll
            for (int i = 0; i < AI; ++i)
#pragma unroll
                for (int j = 0; j < 4; ++j) {
                    const int dd  = j * 16 + ln;        // d within head
                    const int gm0 = m0 + wr * (AI * 16) + i * 16 + g * 4;
                    const int b = gm0 >> 11, t0 = gm0 & 2047;
                    const int tile = t0 >> 6, tt = t0 & 63;
                    const int ks = tt >> 4, hi2 = (tt >> 3) & 1, e = tt & 7;
                    const int j32 = dd >> 5, qc = dd & 31;
                    ushort4 pk;
                    pk.x = f2bf(acc[i][j][0] + bj[j]); pk.y = f2bf(acc[i][j][1] + bj[j]);
                    pk.z = f2bf(acc[i][j][2] + bj[j]); pk.w = f2bf(acc[i][j][3] + bj[j]);
                    const size_t off = (size_t)(b * Hz + h) * (Tz * Dz)
                                     + tile * 4096 + ((j32 * 4 + ks) * 2 + hi2) * 256 + qc * 8 + e;
                    *(ushort4*)&vd[off] = pk;   // e in {0,4}: 8B-aligned, in-chunk
                }
        } else {
            // Q -> [B,H,T,D] rows; K -> fragment-linear Kf (LDS transpose)
            us* dst = (sel == 0) ? (us*)out0 : (us*)out1;
            us* scrw = ((us*)As) + w * (16 * 72);  // 2.25KB/wave scratch (<= 18KB)
            const int row16 = l & 15, ch = l >> 4;
#pragma unroll
            for (int i = 0; i < AI; ++i) {
#pragma unroll
                for (int j = 0; j < 4; ++j)
#pragma unroll
                    for (int r = 0; r < 4; ++r) {
                        float v = acc[i][j][r] + bj[j];
                        if (sel == 0) v *= QSC;
                        scrw[(g * 4 + r) * 72 + j * 16 + ln] = f2bf(v);
                    }
                // same-wave LDS ordering: reads below see this wave's writes
                const int gm = m0 + wr * (AI * 16) + i * 16 + row16;
                const int b = gm >> 11, tt = gm & 2047;
                bf16x8 v0 = *(const bf16x8*)&scrw[row16 * 72 + ch * 8];
                bf16x8 v1 = *(const bf16x8*)&scrw[row16 * 72 + (ch + 4) * 8];
                if (sel == 0) {
                    const size_t base = (size_t)((b * Hz + h) * Tz + tt) * Dz;
                    *(bf16x8*)&dst[base + ch * 8] = v0;
                    *(bf16x8*)&dst[base + (ch + 4) * 8] = v1;
                } else {
                    const int tile = tt >> 6, rr = tt & 63;
                    const int kb32 = rr >> 5, qc = rr & 31;
                    const size_t tb = (size_t)(b * Hz + h) * (Tz * Dz) + tile * 4096;
                    *(bf16x8*)&dst[tb + (kb32 * 8 + ch) * 256 + qc * 8]       = v0;
                    *(bf16x8*)&dst[tb + (kb32 * 8 + ch + 4) * 256 + qc * 8]   = v1;
                }
            }
        }
    } else {
        float* od = (float*)out0;
#pragma unroll
        for (int i = 0; i < AI; ++i)
#pragma unroll
            for (int j = 0; j < 4; ++j) {
                const int gn = n0 + wc * 64 + j * 16 + ln;
                const float bjv = b0[gn];
#pragma unroll
                for (int r = 0; r < 4; ++r) {
                    const int gm = m0 + wr * (AI * 16) + i * 16 + g * 4 + r;
                    od[(size_t)gm * 1024 + gn] = acc[i][j][r] + bjv;
                }
            }
    }
}

// ---------------------------------------------------------------------------
// Wave-flash attention (r6, passing): 32x32 swapped QK^T, in-register
// softmax (T12), fragment-linear K/V, 4-way K-split + LDS merge tree.
// __launch_bounds__(256,3): do not raise (r1: ~85-reg budget => 673MB spill).
// ---------------------------------------------------------------------------
__global__ __launch_bounds__(256, 3)
void attn_wave(const us* __restrict__ Q, const us* __restrict__ K,
               const us* __restrict__ Vt, us* __restrict__ AO)
{
    __shared__ float Om[2][32][65];   // merge: 16.6 KB
    __shared__ float Lw[2][32];       // merge row-sums

    const int t = threadIdx.x, w = t >> 6, l = t & 63;
    const int qc = l & 31;            // q-col (QK) / d-col (PV)
    const int hi = l >> 5;
    const int hi8 = hi << 3, hi4 = hi << 2;
    const int bh = blockIdx.x;                       // head pinned to XCD bh%8
    const int chunk = 63 - (int)blockIdx.y;          // heavy first
    const int q0 = chunk * 32;
    const size_t hb = (size_t)bh * Tz * Dz;

    const int ntiles = (q0 >> 6) + 1;
    const int it0 = (w * ntiles) >> 2;               // wave w: [it0, it1)
    const int it1 = ((w + 1) * ntiles) >> 2;

    // Q B-frags: n = q0+qc, k-pos (hi,j) -> d = kb*16 + 8hi + j  (rows: [T,D])
    bf16x8 qf[4];
#pragma unroll
    for (int kb = 0; kb < 4; ++kb)
        qf[kb] = *(const bf16x8*)&Q[hb + (size_t)(q0 + qc) * Dz + kb * 16 + hi8];

    f32x16 o0, o1;                    // O[q(reg,hi)][d = {0,1}*32 + qc]
    float lrs = 0.f;                  // own-half row-sum for q = q0+qc
#pragma unroll
    for (int r = 0; r < 16; ++r) { o0[r] = 0.f; o1[r] = 0.f; }

    const int ktLast = (q0 >> 6) << 6;
    const float SMAX = 20.f;          // static max (log2 domain)

    for (int it = it0; it < it1; ++it) {
        const int kt = it * 64;
        const size_t tb = hb + (size_t)it * 4096;    // fragment-linear tile base

        // K A-frags: contiguous, lane l at +l*8 elems
        bf16x8 kf[2][4];
#pragma unroll
        for (int kb32 = 0; kb32 < 2; ++kb32)
#pragma unroll
            for (int kb = 0; kb < 4; ++kb)
                kf[kb32][kb] = *(const bf16x8*)&K[tb + (size_t)((kb32 * 4 + kb) * 64 + l) * 8];

        // S^T = K Q^T : col = q, reg-rows = key
        f32x16 s2[2];
#pragma unroll
        for (int r = 0; r < 16; ++r) { s2[0][r] = 0.f; s2[1][r] = 0.f; }
        __builtin_amdgcn_s_setprio(1);
#pragma unroll
        for (int kb32 = 0; kb32 < 2; ++kb32)
#pragma unroll
            for (int kb = 0; kb < 4; ++kb)
                s2[kb32] = __builtin_amdgcn_mfma_f32_32x32x16_bf16(kf[kb32][kb], qf[kb], s2[kb32], 0, 0, 0);
        __builtin_amdgcn_s_setprio(0);

        // V B-frags: contiguous; issue now, land during softmax
        bf16x8 vf[2][4];
#pragma unroll
        for (int j32 = 0; j32 < 2; ++j32)
#pragma unroll
            for (int ks = 0; ks < 4; ++ks)
                vf[j32][ks] = *(const bf16x8*)&Vt[tb + (size_t)((j32 * 4 + ks) * 64 + l) * 8];

        if (kt == ktLast) {   // diagonal tile: causal mask (wave-uniform branch)
            const int qv = q0 + qc;
#pragma unroll
            for (int kb32 = 0; kb32 < 2; ++kb32)
#pragma unroll
                for (int r = 0; r < 16; ++r) {
                    const int key = kt + kb32 * 32 + (r & 3) + 8 * (r >> 2) + hi4;
                    if (key > qv) s2[kb32][r] = -__builtin_inff();
                }
        }

        // in-register softmax + P->A-frag transpose (no LDS)
        bf16x8 pf[4];
#pragma unroll
        for (int kb32 = 0; kb32 < 2; ++kb32) {
            unsigned pk[4][2];
#pragma unroll
            for (int sg = 0; sg < 4; ++sg)
#pragma unroll
                for (int u = 0; u < 2; ++u) {
                    const float e0 = fexp2(s2[kb32][sg * 4 + 2 * u]     - SMAX);  // -inf -> 0
                    const float e1 = fexp2(s2[kb32][sg * 4 + 2 * u + 1] - SMAX);
                    lrs += e0 + e1;
                    pk[sg][u] = __builtin_amdgcn_perm(__float_as_uint(e1), __float_as_uint(e0), 0x07060302u);
                }
            // swap(a=even_sg, b=odd_sg): a' = frag dwords j{2u,2u+1}, b' = j{4+2u,5+2u}
#pragma unroll
            for (int kb16 = 0; kb16 < 2; ++kb16) {
                unsigned a0 = pk[2 * kb16][0], b0 = pk[2 * kb16 + 1][0];
                unsigned a1 = pk[2 * kb16][1], b1 = pk[2 * kb16 + 1][1];
                pl32swap(a0, b0);
                pl32swap(a1, b1);
                union { unsigned u[4]; bf16x8 v; } P;
                P.u[0] = a0; P.u[1] = a1; P.u[2] = b0; P.u[3] = b1;
                pf[kb32 * 2 + kb16] = P.v;
            }
        }

        // PV: O[q][d], A = pf (m=q), B = vf (n=d)
        __builtin_amdgcn_s_setprio(1);
#pragma unroll
        for (int ks = 0; ks < 4; ++ks) {
            o0 = __builtin_amdgcn_mfma_f32_32x32x16_bf16(pf[ks], vf[0][ks], o0, 0, 0, 0);
            o1 = __builtin_amdgcn_mfma_f32_32x32x16_bf16(pf[ks], vf[1][ks], o1, 0, 0, 0);
        }
        __builtin_amdgcn_s_setprio(0);
    }

    // combine half row-sums: partner's value arrives in b' on lo, a' on hi.
    {
        unsigned a = __float_as_uint(lrs), b = a;
        pl32swap(a, b);
        lrs += hi ? __uint_as_float(a) : __uint_as_float(b);
    }

    // ---- merge the 4 K-split partials (same static max -> plain sums) ----
    if (w & 1) {       // waves 1,3 park into buf w>>1
        const int buf = w >> 1;
#pragma unroll
        for (int r = 0; r < 16; ++r) {
            const int row = (r & 3) + 8 * (r >> 2) + hi4;
            Om[buf][row][qc]      = o0[r];
            Om[buf][row][32 + qc] = o1[r];
        }
        if (hi == 0) Lw[buf][qc] = lrs;
    }
    __syncthreads();
    if (!(w & 1)) {    // waves 0,2 absorb their odd buddy
        const int buf = w >> 1;
#pragma unroll
        for (int r = 0; r < 16; ++r) {
            const int row = (r & 3) + 8 * (r >> 2) + hi4;
            o0[r] += Om[buf][row][qc];
            o1[r] += Om[buf][row][32 + qc];
        }
        lrs += Lw[buf][qc];
    }
    __syncthreads();
    if (w == 2) {      // park the (2+3) partial for wave 0
#pragma unroll
        for (int r = 0; r < 16; ++r) {
            const int row = (r & 3) + 8 * (r >> 2) + hi4;
            Om[0][row][qc]      = o0[r];
            Om[0][row][32 + qc] = o1[r];
        }
        if (hi == 0) Lw[0][qc] = lrs;
    }
    __syncthreads();
    if (w == 0) {      // final sum, normalize (bpermute broadcast), write
        const int b = bh >> 4, h = bh & 15;
        const float lsum = lrs + Lw[0][qc];   // full row-sum for q = q0+qc
#pragma unroll
        for (int r = 0; r < 16; ++r) {
            const int row = (r & 3) + 8 * (r >> 2) + hi4;
            const float ov0 = o0[r] + Om[0][row][qc];
            const float ov1 = o1[r] + Om[0][row][32 + qc];
            const unsigned lq = __builtin_amdgcn_ds_bpermute(row << 2, __float_as_uint(lsum));
            const float linv = 1.f / __uint_as_float(lq);
            const size_t ob = (size_t)(b * Tz + q0 + row) * Cz + h * Dz + qc;
            AO[ob]      = f2bf(ov0 * linv);
            AO[ob + 32] = f2bf(ov1 * linv);
        }
    }
}

// ---------------------------------------------------------------------------
extern "C" void kernel_launch(void* const* d_in, const int* in_sizes, int n_in,
                              void* d_out, int out_size, void* d_ws, size_t ws_size,
                              hipStream_t stream) {
    const float* x  = (const float*)d_in[0];
    // d_in[1] = att_mask (causal tril) — implied by kernel structure, unused
    const float* wq = (const float*)d_in[2];
    const float* bq = (const float*)d_in[3];
    const float* wk = (const float*)d_in[4];
    const float* bk = (const float*)d_in[5];
    const float* wv = (const float*)d_in[6];
    const float* bv = (const float*)d_in[7];
    const float* wp = (const float*)d_in[8];
    const float* bp = (const float*)d_in[9];
    float* out = (float*)d_out;

    char* wsb = (char*)d_ws;
    us* xb    = (us*)(wsb);                       // 8 MB
    us* wqkvb = (us*)(wsb + (8u  << 20));         // 6 MB
    us* wpb   = (us*)(wsb + (14u << 20));         // 2 MB
    us* Qb    = (us*)(wsb + (17u << 20));         // 8 MB
    us* Kb    = (us*)(wsb + (25u << 20));         // 8 MB (fragment-linear)
    us* Vtb   = (us*)(wsb + (33u << 20));         // 8 MB (fragment-linear)
    us* AOb   = (us*)(wsb + (41u << 20));         // 8 MB

    hipLaunchKernelGGL(cast_all, dim3(8192), dim3(256), 0, stream,
                       x, wq, wk, wv, wp, xb, wqkvb, wpb);

    // fused QKV: [4096 x 3072 x 1024], 128x128 tile, 8 waves (512 thr):
    // 2 blocks/CU x 8 waves = 4 waves/SIMD (r12 best config)
    hipLaunchKernelGGL((mfma_gemm<2, 4, 0>), dim3(24, 32), dim3(512), 0, stream,
                       xb, wqkvb, bq, bk, bv, Qb, Kb, Vtb);

    // attention: 32x32 swapped-QK^T, in-register softmax, contiguous frag loads
    hipLaunchKernelGGL(attn_wave, dim3(32, 64), dim3(256), 0, stream,
                       Qb, Kb, Vtb, AOb);

    // output projection: r7 best config (64x128, 4 waves, 3 blocks/CU)
    hipLaunchKernelGGL((mfma_gemm<2, 2, 1>), dim3(8, 64), dim3(256), 0, stream,
                       AOb, wpb, bp, bp, bp, out, nullptr, nullptr);
}